// Round 11
// baseline (710.378 us; speedup 1.0000x reference)
//
#include <hip/hip_runtime.h>
#include <hip/hip_bf16.h>
#include <math.h>

// Split-bf16 MFMA exact-KNN (K=32) + inverse-squared-distance weighting.
// points:[16384,64] features:[20000,64] targets:[20000] -> out:[16384]
//
// Round 11: 64 q/block (256 blocks) halves the L2/L3 feature traffic
// (the R10 counters show ~6.1 TB/s demand with diminishing occupancy
// returns -> service-bandwidth asymptote). Candidates + sample keys move
// to global d_ws (tiered: big ws -> 64q kernel; medium -> R10 kernel;
// tiny -> fp32 fallback). 4 stationary Q-groups, 32 MFMA / 5-load subtile.

#define NQ   16384
#define MM   20000
#define DD   64
#define KK   32
#define MPAD 20032
#define NCH  (MPAD / 64)   // 313
#define NW   16            // waves per block (R10 + new kernel)
#define QB   32            // R10 queries per block
#define CAP  576           // R10 LDS candidate cap
#define SMPN 2048          // sample rows = chunks 0..31
#define SMPS 2056          // R10 padded u16 stride
#define CAP2 640           // global-candidate cap (E=312, ~6 sigma)

typedef __attribute__((ext_vector_type(8))) short bf16x8;
typedef __attribute__((ext_vector_type(4))) float f32x4;

// ---- workspace layout (bytes) ----
#define OFF_FH 0
#define SZ_FP  (MPAD * DD * 2)
#define OFF_FL (OFF_FH + SZ_FP)
#define OFF_FN (OFF_FL + SZ_FP)
#define SZ_FN  (MPAD * 4)
#define OFF_QH (OFF_FN + SZ_FN)
#define SZ_QP  (NQ * DD * 2)
#define OFF_QL (OFF_QH + SZ_QP)
#define OFF_QN (OFF_QL + SZ_QP)
#define SZ_QN  (NQ * 4)
#define WS_REQ (OFF_QN + SZ_QN)                 // 9,468,160 (16-aligned)
#define OFF_CAND ((size_t)WS_REQ)
#define SZ_CAND  ((size_t)NQ * CAP2 * 8)        // float2 per candidate
#define OFF_CNT  (OFF_CAND + SZ_CAND)
#define WS_FAST  (OFF_CNT + (size_t)NQ * 4)     // ~93.4 MB

__device__ __forceinline__ unsigned int bf16_rne(float x) {
    unsigned int xb = __float_as_uint(x);
    return (xb + 0x7fffu + ((xb >> 16) & 1u)) & 0xffff0000u;
}
__device__ __forceinline__ unsigned enc32(float f) {
    unsigned b = __float_as_uint(f);
    return (b & 0x80000000u) ? ~b : (b | 0x80000000u);
}
__device__ __forceinline__ float dec32(unsigned k) {
    unsigned b = (k & 0x80000000u) ? (k & 0x7FFFFFFFu) : ~k;
    return __uint_as_float(b);
}

__global__ void prep_split(const float* __restrict__ src,
                           unsigned short* __restrict__ ph,
                           unsigned short* __restrict__ pl,
                           float* __restrict__ nrm, int nrows_real) {
    const int e = blockIdx.x * 256 + threadIdx.x;
    const int m = e >> 6;
    const int lane = threadIdx.x & 63;
    const bool real = (m < nrows_real);
    float x = real ? src[e] : 0.f;
    unsigned int hb = bf16_rne(x);
    float xh = __uint_as_float(hb);
    unsigned int lb = bf16_rne(x - xh);
    ph[e] = (unsigned short)(hb >> 16);
    pl[e] = (unsigned short)(lb >> 16);
    float s = x * x;
    #pragma unroll
    for (int o = 32; o >= 1; o >>= 1) s += __shfl_xor(s, o);
    if (lane == 0) nrm[m] = real ? s : __builtin_inff();
}

// ======================= NEW: 64 q/block global-candidate kernel ============

#define SUBTILE4(c_, t_, EPI_)                                                \
  {                                                                           \
    const int rb_ = (c_) * 64 + (t_) * 16;                                    \
    const unsigned short* phh = Fh + (size_t)(rb_ + q) * DD + kof;            \
    const unsigned short* pll = Fl + (size_t)(rb_ + q) * DD + kof;            \
    const bf16x8 Ah0 = *(const bf16x8*)(phh);                                 \
    const bf16x8 Ah1 = *(const bf16x8*)(phh + 32);                            \
    const bf16x8 Al0 = *(const bf16x8*)(pll);                                 \
    const bf16x8 Al1 = *(const bf16x8*)(pll + 32);                            \
    const f32x4  fnv = *(const f32x4*)(fn + rb_ + hgrp * 4);                  \
    const int rb4 = rb_ + hgrp * 4;                                           \
    _Pragma("unroll")                                                         \
    for (int g = 0; g < 4; ++g) {                                             \
      f32x4 a = {0.f, 0.f, 0.f, 0.f};                                         \
      a = __builtin_amdgcn_mfma_f32_16x16x32_bf16(Ah0, qh0[g], a, 0, 0, 0);   \
      a = __builtin_amdgcn_mfma_f32_16x16x32_bf16(Ah1, qh1[g], a, 0, 0, 0);   \
      a = __builtin_amdgcn_mfma_f32_16x16x32_bf16(Ah0, ql0[g], a, 0, 0, 0);   \
      a = __builtin_amdgcn_mfma_f32_16x16x32_bf16(Ah1, ql1[g], a, 0, 0, 0);   \
      a = __builtin_amdgcn_mfma_f32_16x16x32_bf16(Al0, qh0[g], a, 0, 0, 0);   \
      a = __builtin_amdgcn_mfma_f32_16x16x32_bf16(Al1, qh1[g], a, 0, 0, 0);   \
      a = __builtin_amdgcn_mfma_f32_16x16x32_bf16(Al0, ql0[g], a, 0, 0, 0);   \
      a = __builtin_amdgcn_mfma_f32_16x16x32_bf16(Al1, ql1[g], a, 0, 0, 0);   \
      const float s0 = fnv[0] - 2.f * a[0];                                   \
      const float s1 = fnv[1] - 2.f * a[1];                                   \
      const float s2 = fnv[2] - 2.f * a[2];                                   \
      const float s3 = fnv[3] - 2.f * a[3];                                   \
      EPI_(g, s0, s1, s2, s3, rb4)                                            \
    }                                                                         \
  }

#define EPI_KEY(g_, s0_, s1_, s2_, s3_, rb4_) {                               \
    ushort4 kv_;                                                              \
    kv_.x = (unsigned short)(enc32(s0_) >> 16);                               \
    kv_.y = (unsigned short)(enc32(s1_) >> 16);                               \
    kv_.z = (unsigned short)(enc32(s2_) >> 16);                               \
    kv_.w = (unsigned short)(enc32(s3_) >> 16);                               \
    *(ushort4*)&skeys[((g_) * 16 + q) * SMPN + (rb4_)] = kv_;                 \
}

#define EPI_GATE(g_, s0_, s1_, s2_, s3_, rb4_) {                              \
    const float tq_ = tauR[g_];                                               \
    const int qg_ = qbase + (g_) * 16 + q;                                    \
    const float sv_[4] = {s0_, s1_, s2_, s3_};                                \
    _Pragma("unroll")                                                         \
    for (int j_ = 0; j_ < 4; ++j_) {                                          \
      if (sv_[j_] <= tq_) {                                                   \
        const int p_ = atomicAdd(&cnt_g[qg_], 1);                             \
        if (p_ < CAP2) {                                                      \
          float2 e_;                                                          \
          e_.x = sv_[j_];                                                     \
          e_.y = __uint_as_float((unsigned)((rb4_) + j_));                    \
          candv[(size_t)qg_ * CAP2 + p_] = e_;                                \
        }                                                                     \
      }                                                                       \
    }                                                                         \
}

__global__ __launch_bounds__(1024) void knn_global(
    const unsigned short* __restrict__ Fh, const unsigned short* __restrict__ Fl,
    const float* __restrict__ fn,
    const unsigned short* __restrict__ Qh, const unsigned short* __restrict__ Ql,
    const float* __restrict__ qn,
    const float* __restrict__ targets, float* __restrict__ out,
    float2* __restrict__ candv, int* __restrict__ cnt_g)
{
    __shared__ float tau_f[64];

    const int tid  = threadIdx.x;
    const int lane = tid & 63;
    const int w    = tid >> 6;          // 0..15
    const int qbase = blockIdx.x * 64;
    const int q    = lane & 15;
    const int hgrp = lane >> 4;
    const int kof  = hgrp * 8;

    if (tid < 64) cnt_g[qbase + tid] = 0;   // own block's counters only

    // stationary Q^T fragments, 4 query groups (64 VGPR)
    bf16x8 qh0[4], qh1[4], ql0[4], ql1[4];
    #pragma unroll
    for (int g = 0; g < 4; ++g) {
        const int qrow = qbase + g * 16 + q;
        qh0[g] = *(const bf16x8*)(Qh + (size_t)qrow * DD + kof);
        qh1[g] = *(const bf16x8*)(Qh + (size_t)qrow * DD + kof + 32);
        ql0[g] = *(const bf16x8*)(Ql + (size_t)qrow * DD + kof);
        ql1[g] = *(const bf16x8*)(Ql + (size_t)qrow * DD + kof + 32);
    }

    // sample keys overlay this block's candidate region (phase-disjoint)
    unsigned short* skeys = (unsigned short*)(candv + (size_t)qbase * CAP2);

    // ============ phase 1: sample scan (chunks 0..31) -> u16 keys ==========
    #pragma unroll
    for (int cc = 0; cc < 2; ++cc) {
        const int c = w * 2 + cc;
        #pragma unroll
        for (int t = 0; t < 4; ++t) {
            SUBTILE4(c, t, EPI_KEY)
        }
    }
    __syncthreads();   // skeys visible block-wide

    // ---- tau: wave w owns queries w*4..w*4+3; wave holds all 2048 keys ----
    #pragma unroll
    for (int e = 0; e < 4; ++e) {
        const int qq = w * 4 + e;
        unsigned ks[32];
        {
            const ushort4* kp = (const ushort4*)(skeys + qq * SMPN + lane * 32);
            #pragma unroll
            for (int u = 0; u < 8; ++u) {
                const ushort4 kv = kp[u];
                ks[u * 4 + 0] = kv.x; ks[u * 4 + 1] = kv.y;
                ks[u * 4 + 2] = kv.z; ks[u * 4 + 3] = kv.w;
            }
        }
        unsigned lo = 0;
        #pragma unroll
        for (int bit = 15; bit >= 0; --bit) {
            const unsigned trial = lo | (1u << bit);
            int c2 = 0;
            #pragma unroll
            for (int u = 0; u < 32; ++u) c2 += (ks[u] < trial);
            #pragma unroll
            for (int o = 32; o >= 1; o >>= 1) c2 += __shfl_xor(c2, o);
            if (c2 < KK) lo = trial;
        }
        const float tf = (lo >= 0xFFFFu) ? __builtin_inff()
                                         : dec32((lo + 1u) << 16);
        if (lane == 0) tau_f[qq] = tf;
    }
    __syncthreads();

    float tauR[4];
    #pragma unroll
    for (int g = 0; g < 4; ++g) tauR[g] = tau_f[g * 16 + q];

    // ============ phase 2: full scan, register-tau gated global append =====
    for (int c = w; c < NCH; c += 16) {
        #pragma unroll
        for (int t = 0; t < 4; ++t) {
            SUBTILE4(c, t, EPI_GATE)
        }
    }
    __syncthreads();   // drains vmcnt -> candidates + counters visible

    // ============ phase 3: exact rank + weighted sum (4 q per wave) ========
    #pragma unroll
    for (int e = 0; e < 4; ++e) {
        const int q3g = qbase + w * 4 + e;
        const int n   = min(cnt_g[q3g], CAP2);
        const float qnv = qn[q3g];

        float ms[10]; unsigned kk[10]; unsigned mi[10];
        #pragma unroll
        for (int u = 0; u < 10; ++u) {
            const int j = lane + u * 64;
            float sv = __builtin_inff(); unsigned iv = 0xFFFFFFFFu;
            if (j < n) {
                const float2 ev = candv[(size_t)q3g * CAP2 + j];
                sv = ev.x; iv = __float_as_uint(ev.y);
            }
            ms[u] = sv; mi[u] = iv; kk[u] = enc32(sv);
        }
        unsigned lo = 0;
        for (int bit = 31; bit >= 0; --bit) {
            const unsigned trial = lo | (1u << bit);
            int c2 = 0;
            #pragma unroll
            for (int u = 0; u < 10; ++u) c2 += (kk[u] < trial);
            #pragma unroll
            for (int o = 32; o >= 1; o >>= 1) c2 += __shfl_xor(c2, o);
            if (c2 < KK) lo = trial;
        }
        int c0 = 0, tcnt = 0;
        #pragma unroll
        for (int u = 0; u < 10; ++u) { c0 += (kk[u] < lo); tcnt += (kk[u] == lo); }
        #pragma unroll
        for (int o = 32; o >= 1; o >>= 1) {
            c0 += __shfl_xor(c0, o); tcnt += __shfl_xor(tcnt, o);
        }
        const int kprime = KK - c0;
        unsigned ilo = 0xFFFFFFFFu;
        if (tcnt != kprime) {
            ilo = 0;
            for (int bit = 15; bit >= 0; --bit) {
                const unsigned trial = ilo | (1u << bit);
                int c2 = 0;
                #pragma unroll
                for (int u = 0; u < 10; ++u)
                    c2 += ((kk[u] == lo) && (mi[u] < trial));
                #pragma unroll
                for (int o = 32; o >= 1; o >>= 1) c2 += __shfl_xor(c2, o);
                if (c2 < kprime) ilo = trial;
            }
        }
        float nume = 0.f, deno = 0.f;
        #pragma unroll
        for (int u = 0; u < 10; ++u) {
            const bool inc = (kk[u] < lo) || ((kk[u] == lo) && (mi[u] <= ilo));
            if (inc) {
                const float d2 = fmaxf(qnv + ms[u], 0.f);
                const float wv = 1.f / (d2 + 1e-4f);
                nume = fmaf(wv, targets[mi[u]], nume);
                deno += wv;
            }
        }
        #pragma unroll
        for (int o = 32; o >= 1; o >>= 1) {
            nume += __shfl_xor(nume, o);
            deno += __shfl_xor(deno, o);
        }
        if (lane == 0) out[q3g] = nume / fmaxf(deno, 1e-9f);
    }
}

// ======================= R10 kernel (medium-ws fallback, 429 us) ===========

#define SUBTILE2(c_, t_)                                                       \
    const int frow = (c_) * 64 + (t_) * 16 + q;                                \
    const unsigned short* phh = Fh + (size_t)frow * DD + kof;                  \
    const unsigned short* pll = Fl + (size_t)frow * DD + kof;                  \
    const bf16x8 Ah0 = *(const bf16x8*)(phh);                                  \
    const bf16x8 Ah1 = *(const bf16x8*)(phh + 32);                             \
    const bf16x8 Al0 = *(const bf16x8*)(pll);                                  \
    const bf16x8 Al1 = *(const bf16x8*)(pll + 32);                             \
    const f32x4  fnv = *(const f32x4*)(fn + (c_) * 64 + (t_) * 16 + hgrp * 4); \
    f32x4 a0 = {0.f,0.f,0.f,0.f}, b0 = {0.f,0.f,0.f,0.f};                      \
    f32x4 a1 = {0.f,0.f,0.f,0.f}, b1 = {0.f,0.f,0.f,0.f};                      \
    a0 = __builtin_amdgcn_mfma_f32_16x16x32_bf16(Ah0, qh0A, a0, 0, 0, 0);      \
    b0 = __builtin_amdgcn_mfma_f32_16x16x32_bf16(Ah0, ql0A, b0, 0, 0, 0);      \
    a1 = __builtin_amdgcn_mfma_f32_16x16x32_bf16(Ah0, qh0B, a1, 0, 0, 0);      \
    b1 = __builtin_amdgcn_mfma_f32_16x16x32_bf16(Ah0, ql0B, b1, 0, 0, 0);      \
    a0 = __builtin_amdgcn_mfma_f32_16x16x32_bf16(Ah1, qh1A, a0, 0, 0, 0);      \
    b0 = __builtin_amdgcn_mfma_f32_16x16x32_bf16(Ah1, ql1A, b0, 0, 0, 0);      \
    a1 = __builtin_amdgcn_mfma_f32_16x16x32_bf16(Ah1, qh1B, a1, 0, 0, 0);      \
    b1 = __builtin_amdgcn_mfma_f32_16x16x32_bf16(Ah1, ql1B, b1, 0, 0, 0);      \
    a0 = __builtin_amdgcn_mfma_f32_16x16x32_bf16(Al0, qh0A, a0, 0, 0, 0);      \
    b0 = __builtin_amdgcn_mfma_f32_16x16x32_bf16(Al0, ql0A, b0, 0, 0, 0);      \
    a1 = __builtin_amdgcn_mfma_f32_16x16x32_bf16(Al0, qh0B, a1, 0, 0, 0);      \
    b1 = __builtin_amdgcn_mfma_f32_16x16x32_bf16(Al0, ql0B, b1, 0, 0, 0);      \
    a0 = __builtin_amdgcn_mfma_f32_16x16x32_bf16(Al1, qh1A, a0, 0, 0, 0);      \
    b0 = __builtin_amdgcn_mfma_f32_16x16x32_bf16(Al1, ql1A, b0, 0, 0, 0);      \
    a1 = __builtin_amdgcn_mfma_f32_16x16x32_bf16(Al1, qh1B, a1, 0, 0, 0);      \
    b1 = __builtin_amdgcn_mfma_f32_16x16x32_bf16(Al1, ql1B, b1, 0, 0, 0);      \
    const float sA0 = fnv[0] - 2.f * (a0[0] + b0[0]);                          \
    const float sA1 = fnv[1] - 2.f * (a0[1] + b0[1]);                          \
    const float sA2 = fnv[2] - 2.f * (a0[2] + b0[2]);                          \
    const float sA3 = fnv[3] - 2.f * (a0[3] + b0[3]);                          \
    const float sB0 = fnv[0] - 2.f * (a1[0] + b1[0]);                          \
    const float sB1 = fnv[1] - 2.f * (a1[1] + b1[1]);                          \
    const float sB2 = fnv[2] - 2.f * (a1[2] + b1[2]);                          \
    const float sB3 = fnv[3] - 2.f * (a1[3] + b1[3]);                          \
    const int rb4 = (c_) * 64 + (t_) * 16 + hgrp * 4;

#define GATE2(qq_, tau_, s0_, s1_, s2_, s3_) {                                 \
    const float sv_[4] = {s0_, s1_, s2_, s3_};                                 \
    _Pragma("unroll")                                                          \
    for (int j_ = 0; j_ < 4; ++j_) {                                           \
        if (sv_[j_] <= (tau_)) {                                               \
            const int p_ = atomicAdd(&cnt[qq_], 1);                            \
            if (p_ < CAP) {                                                    \
                bufd[(qq_) * CAP + p_] = sv_[j_];                              \
                bufi[(qq_) * CAP + p_] = (unsigned short)(rb4 + j_);           \
            }                                                                  \
        }                                                                      \
    }                                                                          \
}

__global__ __launch_bounds__(1024) void knn_filter32(
    const unsigned short* __restrict__ Fh, const unsigned short* __restrict__ Fl,
    const float* __restrict__ fn,
    const unsigned short* __restrict__ Qh, const unsigned short* __restrict__ Ql,
    const float* __restrict__ qn,
    const float* __restrict__ targets, float* __restrict__ out)
{
    __shared__ __align__(16) unsigned char pool[QB * SMPS * 2];
    __shared__ float tau_f[QB];
    __shared__ int   cnt[QB];

    unsigned short* smp  = (unsigned short*)pool;
    float*          bufd = (float*)pool;
    unsigned short* bufi = (unsigned short*)(pool + QB * CAP * 4);

    const int tid  = threadIdx.x;
    const int lane = tid & 63;
    const int w    = tid >> 6;          // 0..15
    const int qbase = blockIdx.x * QB;
    const int q    = lane & 15;
    const int hgrp = lane >> 4;
    const int kof  = hgrp * 8;

    if (tid < QB) cnt[tid] = 0;

    const int qrow0 = qbase + q;
    const int qrow1 = qbase + 16 + q;
    const bf16x8 qh0A = *(const bf16x8*)(Qh + (size_t)qrow0 * DD + kof);
    const bf16x8 qh1A = *(const bf16x8*)(Qh + (size_t)qrow0 * DD + kof + 32);
    const bf16x8 ql0A = *(const bf16x8*)(Ql + (size_t)qrow0 * DD + kof);
    const bf16x8 ql1A = *(const bf16x8*)(Ql + (size_t)qrow0 * DD + kof + 32);
    const bf16x8 qh0B = *(const bf16x8*)(Qh + (size_t)qrow1 * DD + kof);
    const bf16x8 qh1B = *(const bf16x8*)(Qh + (size_t)qrow1 * DD + kof + 32);
    const bf16x8 ql0B = *(const bf16x8*)(Ql + (size_t)qrow1 * DD + kof);
    const bf16x8 ql1B = *(const bf16x8*)(Ql + (size_t)qrow1 * DD + kof + 32);

    #pragma unroll
    for (int cc = 0; cc < 2; ++cc) {
        const int chunk = w * 2 + cc;
        #pragma unroll
        for (int t = 0; t < 4; ++t) {
            SUBTILE2(chunk, t)
            ushort4 kA, kB;
            kA.x = (unsigned short)(enc32(sA0) >> 16);
            kA.y = (unsigned short)(enc32(sA1) >> 16);
            kA.z = (unsigned short)(enc32(sA2) >> 16);
            kA.w = (unsigned short)(enc32(sA3) >> 16);
            kB.x = (unsigned short)(enc32(sB0) >> 16);
            kB.y = (unsigned short)(enc32(sB1) >> 16);
            kB.z = (unsigned short)(enc32(sB2) >> 16);
            kB.w = (unsigned short)(enc32(sB3) >> 16);
            *(ushort4*)&smp[q * SMPS + rb4]        = kA;
            *(ushort4*)&smp[(16 + q) * SMPS + rb4] = kB;
        }
    }
    __syncthreads();

    #pragma unroll
    for (int e = 0; e < 2; ++e) {
        const int qq = w * 2 + e;
        unsigned short vv[32];
        #pragma unroll
        for (int u = 0; u < 32; ++u) vv[u] = smp[qq * SMPS + lane + u * 64];
        unsigned lo = 0;
        #pragma unroll
        for (int bit = 15; bit >= 0; --bit) {
            const unsigned trial = lo | (1u << bit);
            int c = 0;
            #pragma unroll
            for (int u = 0; u < 32; ++u) c += (vv[u] < trial);
            #pragma unroll
            for (int o = 32; o >= 1; o >>= 1) c += __shfl_xor(c, o);
            if (c < KK) lo = trial;
        }
        const float tf = (lo >= 0xFFFFu) ? __builtin_inff()
                                         : dec32((lo + 1u) << 16);
        if (lane == 0) tau_f[qq] = tf;
    }
    __syncthreads();

    const float tauR0 = tau_f[q];
    const float tauR1 = tau_f[16 + q];
    for (int c = w; c < NCH; c += NW) {
        #pragma unroll
        for (int t = 0; t < 4; ++t) {
            SUBTILE2(c, t)
            GATE2(q,      tauR0, sA0, sA1, sA2, sA3)
            GATE2(16 + q, tauR1, sB0, sB1, sB2, sB3)
        }
    }
    __syncthreads();

    #pragma unroll
    for (int e = 0; e < 2; ++e) {
        const int q3 = w * 2 + e;
        const int n  = min(cnt[q3], CAP);
        const float qnv = qn[qbase + q3];

        float    ms[9]; unsigned kk[9]; unsigned short miu[9];
        #pragma unroll
        for (int u = 0; u < 9; ++u) {
            const int j = lane + u * 64;
            const bool v = (j < n);
            ms[u]  = v ? bufd[q3 * CAP + j] : __builtin_inff();
            miu[u] = v ? bufi[q3 * CAP + j] : (unsigned short)0xFFFFu;
            kk[u]  = enc32(ms[u]);
        }
        unsigned lo = 0;
        for (int bit = 31; bit >= 0; --bit) {
            const unsigned trial = lo | (1u << bit);
            int c = 0;
            #pragma unroll
            for (int u = 0; u < 9; ++u) c += (kk[u] < trial);
            #pragma unroll
            for (int o = 32; o >= 1; o >>= 1) c += __shfl_xor(c, o);
            if (c < KK) lo = trial;
        }
        int c0 = 0, tcnt = 0;
        #pragma unroll
        for (int u = 0; u < 9; ++u) { c0 += (kk[u] < lo); tcnt += (kk[u] == lo); }
        #pragma unroll
        for (int o = 32; o >= 1; o >>= 1) {
            c0 += __shfl_xor(c0, o); tcnt += __shfl_xor(tcnt, o);
        }
        const int kprime = KK - c0;
        unsigned ilo = 0xFFFFu;
        if (tcnt != kprime) {
            ilo = 0;
            for (int bit = 15; bit >= 0; --bit) {
                const unsigned trial = ilo | (1u << bit);
                int c = 0;
                #pragma unroll
                for (int u = 0; u < 9; ++u)
                    c += ((kk[u] == lo) && ((unsigned)miu[u] < trial));
                #pragma unroll
                for (int o = 32; o >= 1; o >>= 1) c += __shfl_xor(c, o);
                if (c < kprime) ilo = trial;
            }
        }
        float nume = 0.f, deno = 0.f;
        #pragma unroll
        for (int u = 0; u < 9; ++u) {
            const bool inc = (kk[u] < lo) ||
                             ((kk[u] == lo) && ((unsigned)miu[u] <= ilo));
            if (inc) {
                const float d2 = fmaxf(qnv + ms[u], 0.f);
                const float wv = 1.f / (d2 + 1e-4f);
                nume = fmaf(wv, targets[miu[u]], nume);
                deno += wv;
            }
        }
        #pragma unroll
        for (int o = 32; o >= 1; o >>= 1) {
            nume += __shfl_xor(nume, o);
            deno += __shfl_xor(deno, o);
        }
        if (lane == 0) out[qbase + q3] = nume / fmaxf(deno, 1e-9f);
    }
}

// ---------------- fallback: round-1 exact fp32 vector kernel ----------------
#define BQ 32
#define WQ 8
__global__ __launch_bounds__(256) void hp_knn_kernel(
    const float* __restrict__ points, const float* __restrict__ features,
    const float* __restrict__ targets, float* __restrict__ out)
{
    __shared__ __align__(16) float Qs[BQ][DD];
    __shared__ float qn_s[BQ];
    __shared__ float topd[BQ][KK];
    __shared__ int   topi[BQ][KK];
    const int tid = threadIdx.x, lane = tid & 63, wv = tid >> 6, qb = wv * WQ;
    {
        const float4* src = (const float4*)(points + (size_t)blockIdx.x * BQ * DD);
        float4* dst = (float4*)&Qs[0][0];
        #pragma unroll
        for (int i = 0; i < (BQ * DD / 4) / 256; ++i) dst[tid + i * 256] = src[tid + i * 256];
    }
    for (int i = tid; i < BQ * KK; i += 256) { (&topd[0][0])[i] = __builtin_inff(); (&topi[0][0])[i] = 0; }
    __syncthreads();
    if (tid < BQ) {
        float s = 0.f;
        #pragma unroll
        for (int d = 0; d < DD; ++d) s = fmaf(Qs[tid][d], Qs[tid][d], s);
        qn_s[tid] = s;
    }
    __syncthreads();
    for (int c = 0; c < (MM + 63) / 64; ++c) {
        const int m = c * 64 + lane, mc = (m < MM) ? m : (MM - 1);
        float f[DD];
        const float4* fr = (const float4*)(features + (size_t)mc * DD);
        #pragma unroll
        for (int b = 0; b < DD / 4; ++b) { float4 v = fr[b]; f[4*b]=v.x; f[4*b+1]=v.y; f[4*b+2]=v.z; f[4*b+3]=v.w; }
        float fnv = 0.f;
        #pragma unroll
        for (int d = 0; d < DD; ++d) fnv = fmaf(f[d], f[d], fnv);
        float d2v[WQ];
        #pragma unroll
        for (int qi = 0; qi < WQ; ++qi) {
            const float4* qr = (const float4*)&Qs[qb + qi][0];
            float a0=0,a1=0,a2=0,a3=0;
            #pragma unroll
            for (int b = 0; b < DD / 4; ++b) {
                float4 q4 = qr[b];
                a0 = fmaf(q4.x, f[4*b], a0); a1 = fmaf(q4.y, f[4*b+1], a1);
                a2 = fmaf(q4.z, f[4*b+2], a2); a3 = fmaf(q4.w, f[4*b+3], a3);
            }
            float d2 = fmaxf(qn_s[qb+qi] + fnv - 2.f*((a0+a1)+(a2+a3)), 0.f);
            d2v[qi] = (m < MM) ? d2 : __builtin_inff();
        }
        #pragma unroll
        for (int qi = 0; qi < WQ; ++qi) {
            const int q = qb + qi;
            unsigned long long ball = __ballot(d2v[qi] < topd[q][KK-1]);
            while (ball) {
                const int j = __builtin_ctzll(ball); ball &= ball - 1;
                const float dval = __shfl(d2v[qi], j); const int mval = c * 64 + j;
                if (lane < KK) {
                    const float cur = topd[q][lane];
                    if (cur > dval) {
                        const float pd = (lane > 0) ? topd[q][lane-1] : -1.f;
                        const int   pi = (lane > 0) ? topi[q][lane-1] : 0;
                        const bool tp = (pd > dval);
                        topd[q][lane] = tp ? pd : dval; topi[q][lane] = tp ? pi : mval;
                    }
                }
            }
        }
    }
    #pragma unroll
    for (int qi = 0; qi < WQ; ++qi) {
        const int q = qb + qi;
        float wsum = 0.f, wt = 0.f;
        if (lane < KK) {
            const float ww = 1.f / (topd[q][lane] + 1e-4f);
            wsum = ww; wt = ww * targets[topi[q][lane]];
        }
        #pragma unroll
        for (int o = 32; o >= 1; o >>= 1) { wsum += __shfl_xor(wsum, o); wt += __shfl_xor(wt, o); }
        if (lane == 0) out[(size_t)blockIdx.x * BQ + q] = wt / fmaxf(wsum, 1e-9f);
    }
}

extern "C" void kernel_launch(void* const* d_in, const int* in_sizes, int n_in,
                              void* d_out, int out_size, void* d_ws, size_t ws_size,
                              hipStream_t stream) {
    const float* points   = (const float*)d_in[0];
    const float* features = (const float*)d_in[1];
    const float* targets  = (const float*)d_in[2];
    float* out = (float*)d_out;

    if (ws_size < (size_t)WS_REQ) {
        hp_knn_kernel<<<dim3(NQ / BQ), dim3(256), 0, stream>>>(points, features, targets, out);
        return;
    }
    char* ws = (char*)d_ws;
    unsigned short* Fh = (unsigned short*)(ws + OFF_FH);
    unsigned short* Fl = (unsigned short*)(ws + OFF_FL);
    float*          fn = (float*)(ws + OFF_FN);
    unsigned short* Qh = (unsigned short*)(ws + OFF_QH);
    unsigned short* Ql = (unsigned short*)(ws + OFF_QL);
    float*          qnp= (float*)(ws + OFF_QN);

    prep_split<<<dim3(MPAD * DD / 256), dim3(256), 0, stream>>>(features, Fh, Fl, fn, MM);
    prep_split<<<dim3(NQ * DD / 256),  dim3(256), 0, stream>>>(points,   Qh, Ql, qnp, NQ);

    if (ws_size >= WS_FAST) {
        float2* candv = (float2*)(ws + OFF_CAND);
        int*    cnt_g = (int*)(ws + OFF_CNT);
        knn_global<<<dim3(NQ / 64), dim3(1024), 0, stream>>>(
            Fh, Fl, fn, Qh, Ql, qnp, targets, out, candv, cnt_g);
    } else {
        knn_filter32<<<dim3(NQ / QB), dim3(1024), 0, stream>>>(
            Fh, Fl, fn, Qh, Ql, qnp, targets, out);
    }
}

// Round 12
// 444.146 us; speedup vs baseline: 1.5994x; 1.5994x over previous
//
#include <hip/hip_runtime.h>
#include <hip/hip_bf16.h>
#include <math.h>

// Split-bf16 MFMA exact-KNN (K=32) + inverse-squared-distance weighting.
// points:[16384,64] features:[20000,64] targets:[20000] -> out:[16384]
//
// Round 12: R10 structure (filter-then-rank, 32 q/block, LDS candidates,
// 1024 thr) + inline-asm software-pipelined feature loads in phase 2:
// issue subtile i+1's 5 global_load_dwordx4 (asm, un-sinkable), then
// s_waitcnt vmcnt(5) + sched_barrier(0), then compute subtile i.
// Counted vmcnt never drains to 0 mid-loop. MFMA order bit-identical to
// R10 in both phases (tau coverage + absmax preserved).

#define NQ   16384
#define MM   20000
#define DD   64
#define KK   32
#define MPAD 20032
#define NCH  (MPAD / 64)   // 313
#define NW   16            // waves per block
#define QB   32            // queries per block
#define CAP  576
#define SMPS 2056          // padded u16 sample stride

typedef __attribute__((ext_vector_type(8))) short bf16x8;
typedef __attribute__((ext_vector_type(4))) float f32x4;

// ---- workspace layout (bytes) ----
#define OFF_FH 0
#define SZ_FP  (MPAD * DD * 2)
#define OFF_FL (OFF_FH + SZ_FP)
#define OFF_FN (OFF_FL + SZ_FP)
#define SZ_FN  (MPAD * 4)
#define OFF_QH (OFF_FN + SZ_FN)
#define SZ_QP  (NQ * DD * 2)
#define OFF_QL (OFF_QH + SZ_QP)
#define OFF_QN (OFF_QL + SZ_QP)
#define SZ_QN  (NQ * 4)
#define WS_REQ (OFF_QN + SZ_QN)

__device__ __forceinline__ unsigned int bf16_rne(float x) {
    unsigned int xb = __float_as_uint(x);
    return (xb + 0x7fffu + ((xb >> 16) & 1u)) & 0xffff0000u;
}
__device__ __forceinline__ unsigned enc32(float f) {
    unsigned b = __float_as_uint(f);
    return (b & 0x80000000u) ? ~b : (b | 0x80000000u);
}
__device__ __forceinline__ float dec32(unsigned k) {
    unsigned b = (k & 0x80000000u) ? (k & 0x7FFFFFFFu) : ~k;
    return __uint_as_float(b);
}

__global__ void prep_split(const float* __restrict__ src,
                           unsigned short* __restrict__ ph,
                           unsigned short* __restrict__ pl,
                           float* __restrict__ nrm, int nrows_real) {
    const int e = blockIdx.x * 256 + threadIdx.x;
    const int m = e >> 6;
    const int lane = threadIdx.x & 63;
    const bool real = (m < nrows_real);
    float x = real ? src[e] : 0.f;
    unsigned int hb = bf16_rne(x);
    float xh = __uint_as_float(hb);
    unsigned int lb = bf16_rne(x - xh);
    ph[e] = (unsigned short)(hb >> 16);
    pl[e] = (unsigned short)(lb >> 16);
    float s = x * x;
    #pragma unroll
    for (int o = 32; o >= 1; o >>= 1) s += __shfl_xor(s, o);
    if (lane == 0) nrm[m] = real ? s : __builtin_inff();
}

// ---- pipeline bundle: P##_h0 _h1 _l0 _l1 (bf16x8), P##_fn (f32x4), P##_rb --

// plain (compiler) load of one subtile into bundle P — used in phase 1
#define LOADP(P, c_, t_) {                                                    \
    const int rb_ = (c_) * 64 + (t_) * 16;                                    \
    const unsigned short* ph_ = Fh + (size_t)(rb_ + q) * DD + kof;            \
    const unsigned short* pl_ = Fl + (size_t)(rb_ + q) * DD + kof;            \
    P##_h0 = *(const bf16x8*)ph_;  P##_h1 = *(const bf16x8*)(ph_ + 32);       \
    P##_l0 = *(const bf16x8*)pl_;  P##_l1 = *(const bf16x8*)(pl_ + 32);       \
    P##_fn = *(const f32x4*)(fn + rb_ + hgrp * 4);                            \
    P##_rb = rb_;                                                             \
}

// asm load of subtile index s_ (wave-strided chunk decomposition) into P
#define ISSUE(P, s_) {                                                        \
    const int ch_ = w + ((s_) >> 2) * NW;                                     \
    const int rb_ = ch_ * 64 + ((s_) & 3) * 16;                               \
    unsigned long long ah_ = (unsigned long long)(Fh + (size_t)(rb_ + q) * DD + kof); \
    unsigned long long al_ = (unsigned long long)(Fl + (size_t)(rb_ + q) * DD + kof); \
    unsigned long long af_ = (unsigned long long)(fn + rb_ + hgrp * 4);       \
    asm volatile("global_load_dwordx4 %0, %1, off" : "=v"(P##_h0) : "v"(ah_)); \
    asm volatile("global_load_dwordx4 %0, %1, off offset:64" : "=v"(P##_h1) : "v"(ah_)); \
    asm volatile("global_load_dwordx4 %0, %1, off" : "=v"(P##_l0) : "v"(al_)); \
    asm volatile("global_load_dwordx4 %0, %1, off offset:64" : "=v"(P##_l1) : "v"(al_)); \
    asm volatile("global_load_dwordx4 %0, %1, off" : "=v"(P##_fn) : "v"(af_)); \
    P##_rb = rb_;                                                             \
}

#define WAITV(N_) { asm volatile("s_waitcnt vmcnt(" #N_ ")");                 \
                    __builtin_amdgcn_sched_barrier(0); }

// 16 MFMA, order bit-identical to R10; defines sA0..sA3, sB0..sB3, rb4
#define MFMA16(P)                                                              \
    f32x4 a0 = {0.f,0.f,0.f,0.f}, b0 = {0.f,0.f,0.f,0.f};                      \
    f32x4 a1 = {0.f,0.f,0.f,0.f}, b1 = {0.f,0.f,0.f,0.f};                      \
    a0 = __builtin_amdgcn_mfma_f32_16x16x32_bf16(P##_h0, qh0A, a0, 0, 0, 0);   \
    b0 = __builtin_amdgcn_mfma_f32_16x16x32_bf16(P##_h0, ql0A, b0, 0, 0, 0);   \
    a1 = __builtin_amdgcn_mfma_f32_16x16x32_bf16(P##_h0, qh0B, a1, 0, 0, 0);   \
    b1 = __builtin_amdgcn_mfma_f32_16x16x32_bf16(P##_h0, ql0B, b1, 0, 0, 0);   \
    a0 = __builtin_amdgcn_mfma_f32_16x16x32_bf16(P##_h1, qh1A, a0, 0, 0, 0);   \
    b0 = __builtin_amdgcn_mfma_f32_16x16x32_bf16(P##_h1, ql1A, b0, 0, 0, 0);   \
    a1 = __builtin_amdgcn_mfma_f32_16x16x32_bf16(P##_h1, qh1B, a1, 0, 0, 0);   \
    b1 = __builtin_amdgcn_mfma_f32_16x16x32_bf16(P##_h1, ql1B, b1, 0, 0, 0);   \
    a0 = __builtin_amdgcn_mfma_f32_16x16x32_bf16(P##_l0, qh0A, a0, 0, 0, 0);   \
    b0 = __builtin_amdgcn_mfma_f32_16x16x32_bf16(P##_l0, ql0A, b0, 0, 0, 0);   \
    a1 = __builtin_amdgcn_mfma_f32_16x16x32_bf16(P##_l0, qh0B, a1, 0, 0, 0);   \
    b1 = __builtin_amdgcn_mfma_f32_16x16x32_bf16(P##_l0, ql0B, b1, 0, 0, 0);   \
    a0 = __builtin_amdgcn_mfma_f32_16x16x32_bf16(P##_l1, qh1A, a0, 0, 0, 0);   \
    b0 = __builtin_amdgcn_mfma_f32_16x16x32_bf16(P##_l1, ql1A, b0, 0, 0, 0);   \
    a1 = __builtin_amdgcn_mfma_f32_16x16x32_bf16(P##_l1, qh1B, a1, 0, 0, 0);   \
    b1 = __builtin_amdgcn_mfma_f32_16x16x32_bf16(P##_l1, ql1B, b1, 0, 0, 0);   \
    const float sA0 = P##_fn[0] - 2.f * (a0[0] + b0[0]);                       \
    const float sA1 = P##_fn[1] - 2.f * (a0[1] + b0[1]);                       \
    const float sA2 = P##_fn[2] - 2.f * (a0[2] + b0[2]);                       \
    const float sA3 = P##_fn[3] - 2.f * (a0[3] + b0[3]);                       \
    const float sB0 = P##_fn[0] - 2.f * (a1[0] + b1[0]);                       \
    const float sB1 = P##_fn[1] - 2.f * (a1[1] + b1[1]);                       \
    const float sB2 = P##_fn[2] - 2.f * (a1[2] + b1[2]);                       \
    const float sB3 = P##_fn[3] - 2.f * (a1[3] + b1[3]);                       \
    const int rb4 = P##_rb + hgrp * 4;

#define GATE2(qq_, tau_, s0_, s1_, s2_, s3_) {                                 \
    const float sv_[4] = {s0_, s1_, s2_, s3_};                                 \
    _Pragma("unroll")                                                          \
    for (int j_ = 0; j_ < 4; ++j_) {                                           \
        if (sv_[j_] <= (tau_)) {                                               \
            const int p_ = atomicAdd(&cnt[qq_], 1);                            \
            if (p_ < CAP) {                                                    \
                bufd[(qq_) * CAP + p_] = sv_[j_];                              \
                bufi[(qq_) * CAP + p_] = (unsigned short)(rb4 + j_);           \
            }                                                                  \
        }                                                                      \
    }                                                                          \
}

__global__ __launch_bounds__(1024) void knn_filter32(
    const unsigned short* __restrict__ Fh, const unsigned short* __restrict__ Fl,
    const float* __restrict__ fn,
    const unsigned short* __restrict__ Qh, const unsigned short* __restrict__ Ql,
    const float* __restrict__ qn,
    const float* __restrict__ targets, float* __restrict__ out)
{
    // pool: phase1 = smp u16[32][SMPS]; phase2/3 = bufd f32[32][CAP] + bufi u16
    __shared__ __align__(16) unsigned char pool[QB * SMPS * 2];
    __shared__ float tau_f[QB];
    __shared__ int   cnt[QB];

    unsigned short* smp  = (unsigned short*)pool;
    float*          bufd = (float*)pool;
    unsigned short* bufi = (unsigned short*)(pool + QB * CAP * 4);

    const int tid  = threadIdx.x;
    const int lane = tid & 63;
    const int w    = tid >> 6;          // 0..15
    const int qbase = blockIdx.x * QB;
    const int q    = lane & 15;
    const int hgrp = lane >> 4;
    const int kof  = hgrp * 8;

    if (tid < QB) cnt[tid] = 0;

    // stationary Q^T fragments, two query groups
    const int qrow0 = qbase + q;
    const int qrow1 = qbase + 16 + q;
    const bf16x8 qh0A = *(const bf16x8*)(Qh + (size_t)qrow0 * DD + kof);
    const bf16x8 qh1A = *(const bf16x8*)(Qh + (size_t)qrow0 * DD + kof + 32);
    const bf16x8 ql0A = *(const bf16x8*)(Ql + (size_t)qrow0 * DD + kof);
    const bf16x8 ql1A = *(const bf16x8*)(Ql + (size_t)qrow0 * DD + kof + 32);
    const bf16x8 qh0B = *(const bf16x8*)(Qh + (size_t)qrow1 * DD + kof);
    const bf16x8 qh1B = *(const bf16x8*)(Qh + (size_t)qrow1 * DD + kof + 32);
    const bf16x8 ql0B = *(const bf16x8*)(Ql + (size_t)qrow1 * DD + kof);
    const bf16x8 ql1B = *(const bf16x8*)(Ql + (size_t)qrow1 * DD + kof + 32);

    // pipeline bundles
    bf16x8 A_h0, A_h1, A_l0, A_l1; f32x4 A_fn; int A_rb;
    bf16x8 B_h0, B_h1, B_l0, B_l1; f32x4 B_fn; int B_rb;

    // ============ phase 1: sample scan (chunks 0..31) -> u16 keys ==========
    #pragma unroll
    for (int cc = 0; cc < 2; ++cc) {
        const int chunk = w * 2 + cc;
        #pragma unroll
        for (int t = 0; t < 4; ++t) {
            LOADP(A, chunk, t)
            MFMA16(A)
            ushort4 kA, kB;
            kA.x = (unsigned short)(enc32(sA0) >> 16);
            kA.y = (unsigned short)(enc32(sA1) >> 16);
            kA.z = (unsigned short)(enc32(sA2) >> 16);
            kA.w = (unsigned short)(enc32(sA3) >> 16);
            kB.x = (unsigned short)(enc32(sB0) >> 16);
            kB.y = (unsigned short)(enc32(sB1) >> 16);
            kB.z = (unsigned short)(enc32(sB2) >> 16);
            kB.w = (unsigned short)(enc32(sB3) >> 16);
            *(ushort4*)&smp[q * SMPS + rb4]        = kA;
            *(ushort4*)&smp[(16 + q) * SMPS + rb4] = kB;
        }
    }
    __syncthreads();

    // ---- tau per query: 16-bit count-select; wave w owns queries 2w, 2w+1
    #pragma unroll
    for (int e = 0; e < 2; ++e) {
        const int qq = w * 2 + e;
        unsigned short vv[32];
        #pragma unroll
        for (int u = 0; u < 32; ++u) vv[u] = smp[qq * SMPS + lane + u * 64];
        unsigned lo = 0;
        #pragma unroll
        for (int bit = 15; bit >= 0; --bit) {
            const unsigned trial = lo | (1u << bit);
            int c = 0;
            #pragma unroll
            for (int u = 0; u < 32; ++u) c += (vv[u] < trial);
            #pragma unroll
            for (int o = 32; o >= 1; o >>= 1) c += __shfl_xor(c, o);
            if (c < KK) lo = trial;
        }
        const float tf = (lo >= 0xFFFFu) ? __builtin_inff()
                                         : dec32((lo + 1u) << 16);
        if (lane == 0) tau_f[qq] = tf;
    }
    __syncthreads();   // smp dead; candidate buffers take over; vmcnt drained

    // ============ phase 2: asm-pipelined full scan =========================
    const float tauR0 = tau_f[q];
    const float tauR1 = tau_f[16 + q];
    {
        const int ncw = (NCH - w + NW - 1) / NW;   // 20 (w<=8) or 19
        const int n2  = ncw * 4;                   // 80 or 76 — even
        ISSUE(A, 0)
        for (int s = 0; s + 1 < n2; s += 2) {
            ISSUE(B, s + 1)
            WAITV(5)
            { MFMA16(A)
              GATE2(q,      tauR0, sA0, sA1, sA2, sA3)
              GATE2(16 + q, tauR1, sB0, sB1, sB2, sB3) }
            if (s + 2 < n2) { ISSUE(A, s + 2) WAITV(5) }
            else            { WAITV(0) }
            { MFMA16(B)
              GATE2(q,      tauR0, sA0, sA1, sA2, sA3)
              GATE2(16 + q, tauR1, sB0, sB1, sB2, sB3) }
        }
    }
    __syncthreads();

    // ============ phase 3: exact rank + weighted sum (2 q per wave) ========
    #pragma unroll
    for (int e = 0; e < 2; ++e) {
        const int q3 = w * 2 + e;
        const int n  = min(cnt[q3], CAP);
        const float qnv = qn[qbase + q3];

        float    ms[9]; unsigned kk[9]; unsigned short miu[9];
        #pragma unroll
        for (int u = 0; u < 9; ++u) {
            const int j = lane + u * 64;
            const bool v = (j < n);
            ms[u]  = v ? bufd[q3 * CAP + j] : __builtin_inff();
            miu[u] = v ? bufi[q3 * CAP + j] : (unsigned short)0xFFFFu;
            kk[u]  = enc32(ms[u]);
        }
        unsigned lo = 0;
        for (int bit = 31; bit >= 0; --bit) {
            const unsigned trial = lo | (1u << bit);
            int c = 0;
            #pragma unroll
            for (int u = 0; u < 9; ++u) c += (kk[u] < trial);
            #pragma unroll
            for (int o = 32; o >= 1; o >>= 1) c += __shfl_xor(c, o);
            if (c < KK) lo = trial;
        }
        int c0 = 0, tcnt = 0;
        #pragma unroll
        for (int u = 0; u < 9; ++u) { c0 += (kk[u] < lo); tcnt += (kk[u] == lo); }
        #pragma unroll
        for (int o = 32; o >= 1; o >>= 1) {
            c0 += __shfl_xor(c0, o); tcnt += __shfl_xor(tcnt, o);
        }
        const int kprime = KK - c0;
        unsigned ilo = 0xFFFFu;
        if (tcnt != kprime) {
            ilo = 0;
            for (int bit = 15; bit >= 0; --bit) {
                const unsigned trial = ilo | (1u << bit);
                int c = 0;
                #pragma unroll
                for (int u = 0; u < 9; ++u)
                    c += ((kk[u] == lo) && ((unsigned)miu[u] < trial));
                #pragma unroll
                for (int o = 32; o >= 1; o >>= 1) c += __shfl_xor(c, o);
                if (c < kprime) ilo = trial;
            }
        }
        float nume = 0.f, deno = 0.f;
        #pragma unroll
        for (int u = 0; u < 9; ++u) {
            const bool inc = (kk[u] < lo) ||
                             ((kk[u] == lo) && ((unsigned)miu[u] <= ilo));
            if (inc) {
                const float d2 = fmaxf(qnv + ms[u], 0.f);
                const float wv = 1.f / (d2 + 1e-4f);
                nume = fmaf(wv, targets[miu[u]], nume);
                deno += wv;
            }
        }
        #pragma unroll
        for (int o = 32; o >= 1; o >>= 1) {
            nume += __shfl_xor(nume, o);
            deno += __shfl_xor(deno, o);
        }
        if (lane == 0) out[qbase + q3] = nume / fmaxf(deno, 1e-9f);
    }
}

// ---------------- fallback: round-1 exact fp32 vector kernel ----------------
#define BQ 32
#define WQ 8
__global__ __launch_bounds__(256) void hp_knn_kernel(
    const float* __restrict__ points, const float* __restrict__ features,
    const float* __restrict__ targets, float* __restrict__ out)
{
    __shared__ __align__(16) float Qs[BQ][DD];
    __shared__ float qn_s[BQ];
    __shared__ float topd[BQ][KK];
    __shared__ int   topi[BQ][KK];
    const int tid = threadIdx.x, lane = tid & 63, wv = tid >> 6, qb = wv * WQ;
    {
        const float4* src = (const float4*)(points + (size_t)blockIdx.x * BQ * DD);
        float4* dst = (float4*)&Qs[0][0];
        #pragma unroll
        for (int i = 0; i < (BQ * DD / 4) / 256; ++i) dst[tid + i * 256] = src[tid + i * 256];
    }
    for (int i = tid; i < BQ * KK; i += 256) { (&topd[0][0])[i] = __builtin_inff(); (&topi[0][0])[i] = 0; }
    __syncthreads();
    if (tid < BQ) {
        float s = 0.f;
        #pragma unroll
        for (int d = 0; d < DD; ++d) s = fmaf(Qs[tid][d], Qs[tid][d], s);
        qn_s[tid] = s;
    }
    __syncthreads();
    for (int c = 0; c < (MM + 63) / 64; ++c) {
        const int m = c * 64 + lane, mc = (m < MM) ? m : (MM - 1);
        float f[DD];
        const float4* fr = (const float4*)(features + (size_t)mc * DD);
        #pragma unroll
        for (int b = 0; b < DD / 4; ++b) { float4 v = fr[b]; f[4*b]=v.x; f[4*b+1]=v.y; f[4*b+2]=v.z; f[4*b+3]=v.w; }
        float fnv = 0.f;
        #pragma unroll
        for (int d = 0; d < DD; ++d) fnv = fmaf(f[d], f[d], fnv);
        float d2v[WQ];
        #pragma unroll
        for (int qi = 0; qi < WQ; ++qi) {
            const float4* qr = (const float4*)&Qs[qb + qi][0];
            float a0=0,a1=0,a2=0,a3=0;
            #pragma unroll
            for (int b = 0; b < DD / 4; ++b) {
                float4 q4 = qr[b];
                a0 = fmaf(q4.x, f[4*b], a0); a1 = fmaf(q4.y, f[4*b+1], a1);
                a2 = fmaf(q4.z, f[4*b+2], a2); a3 = fmaf(q4.w, f[4*b+3], a3);
            }
            float d2 = fmaxf(qn_s[qb+qi] + fnv - 2.f*((a0+a1)+(a2+a3)), 0.f);
            d2v[qi] = (m < MM) ? d2 : __builtin_inff();
        }
        #pragma unroll
        for (int qi = 0; qi < WQ; ++qi) {
            const int q = qb + qi;
            unsigned long long ball = __ballot(d2v[qi] < topd[q][KK-1]);
            while (ball) {
                const int j = __builtin_ctzll(ball); ball &= ball - 1;
                const float dval = __shfl(d2v[qi], j); const int mval = c * 64 + j;
                if (lane < KK) {
                    const float cur = topd[q][lane];
                    if (cur > dval) {
                        const float pd = (lane > 0) ? topd[q][lane-1] : -1.f;
                        const int   pi = (lane > 0) ? topi[q][lane-1] : 0;
                        const bool tp = (pd > dval);
                        topd[q][lane] = tp ? pd : dval; topi[q][lane] = tp ? pi : mval;
                    }
                }
            }
        }
    }
    #pragma unroll
    for (int qi = 0; qi < WQ; ++qi) {
        const int q = qb + qi;
        float wsum = 0.f, wt = 0.f;
        if (lane < KK) {
            const float ww = 1.f / (topd[q][lane] + 1e-4f);
            wsum = ww; wt = ww * targets[topi[q][lane]];
        }
        #pragma unroll
        for (int o = 32; o >= 1; o >>= 1) { wsum += __shfl_xor(wsum, o); wt += __shfl_xor(wt, o); }
        if (lane == 0) out[(size_t)blockIdx.x * BQ + q] = wt / fmaxf(wsum, 1e-9f);
    }
}

extern "C" void kernel_launch(void* const* d_in, const int* in_sizes, int n_in,
                              void* d_out, int out_size, void* d_ws, size_t ws_size,
                              hipStream_t stream) {
    const float* points   = (const float*)d_in[0];
    const float* features = (const float*)d_in[1];
    const float* targets  = (const float*)d_in[2];
    float* out = (float*)d_out;

    if (ws_size < (size_t)WS_REQ) {
        hp_knn_kernel<<<dim3(NQ / BQ), dim3(256), 0, stream>>>(points, features, targets, out);
        return;
    }
    char* ws = (char*)d_ws;
    unsigned short* Fh = (unsigned short*)(ws + OFF_FH);
    unsigned short* Fl = (unsigned short*)(ws + OFF_FL);
    float*          fn = (float*)(ws + OFF_FN);
    unsigned short* Qh = (unsigned short*)(ws + OFF_QH);
    unsigned short* Ql = (unsigned short*)(ws + OFF_QL);
    float*          qnp= (float*)(ws + OFF_QN);

    prep_split<<<dim3(MPAD * DD / 256), dim3(256), 0, stream>>>(features, Fh, Fl, fn, MM);
    prep_split<<<dim3(NQ * DD / 256),  dim3(256), 0, stream>>>(points,   Qh, Ql, qnp, NQ);
    knn_filter32<<<dim3(NQ / QB), dim3(1024), 0, stream>>>(Fh, Fl, fn, Qh, Ql, qnp, targets, out);
}